// Round 2
// baseline (47.429 us; speedup 1.0000x reference)
//
#include <hip/hip_runtime.h>
#include <hip/hip_bf16.h>
#include <math.h>
#include <stdint.h>

#define NS 8192       // samples
#define DD 1024       // feature dim
#define NP 512        // prototypes
#define NPARTS 8      // 4 col-blocks * 2 wave-col-halves
#define EPSF 1e-9f
#define BIGF 3.0e38f

typedef __attribute__((ext_vector_type(8))) short bf16x8;
typedef __attribute__((ext_vector_type(4))) float f32x4;

__device__ inline unsigned short f32_to_bf16(float f) {
    uint32_t u = __builtin_bit_cast(uint32_t, f);
    uint32_t r = (u + 0x7FFFu + ((u >> 16) & 1u)) >> 16;
    return (unsigned short)r;
}

// One block per row (x rows then proto rows): convert to bf16, compute sum of squares (f32).
__global__ __launch_bounds__(256) void prep_kernel(
    const float* __restrict__ x, const float* __restrict__ protos,
    unsigned short* __restrict__ xb, unsigned short* __restrict__ pb,
    float* __restrict__ xsq, float* __restrict__ psq)
{
    int row = blockIdx.x;
    const float* src;
    unsigned short* dstb;
    float* dsts;
    if (row < NS) {
        src = x + (size_t)row * DD; dstb = xb + (size_t)row * DD; dsts = xsq + row;
    } else {
        int r = row - NS;
        src = protos + (size_t)r * DD; dstb = pb + (size_t)r * DD; dsts = psq + r;
    }
    int t = threadIdx.x;
    float4 v = ((const float4*)src)[t];
    float ss = v.x * v.x + v.y * v.y + v.z * v.z + v.w * v.w;
    ushort4 o;
    o.x = f32_to_bf16(v.x); o.y = f32_to_bf16(v.y);
    o.z = f32_to_bf16(v.z); o.w = f32_to_bf16(v.w);
    ((ushort4*)dstb)[t] = o;
    // reduce ss over the block
    for (int off = 32; off; off >>= 1) ss += __shfl_down(ss, off);
    __shared__ float red[4];
    if ((t & 63) == 0) red[t >> 6] = ss;
    __syncthreads();
    if (t == 0) dsts[0] = red[0] + red[1] + red[2] + red[3];
}

// 128x128 bf16 MFMA tile, BK=64, 4 waves (2x2 of 64x64), global_load_lds staging.
// Fused epilogue: per-row masked mins over this block's 128 cols -> partial slabs.
__global__ __launch_bounds__(256) void glvq_gemm(
    const unsigned short* __restrict__ Xb, const unsigned short* __restrict__ Pb,
    const float* __restrict__ xsq, const float* __restrict__ psq,
    const int* __restrict__ y,
    float* __restrict__ d1p, float* __restrict__ d2p)
{
    __shared__ unsigned short As[128 * 64];
    __shared__ unsigned short Bs[128 * 64];

    const int tid  = threadIdx.x;
    const int lane = tid & 63;
    const int wid  = tid >> 6;
    const int wr = wid >> 1, wc = wid & 1;
    const int m0 = blockIdx.x * 128;
    const int n0 = blockIdx.y * 128;

    const int srow = lane >> 3;          // 0..7 within 8-row chunk
    const int scol = (lane & 7) * 8;     // element offset of 16B chunk in a 64-elem row

    f32x4 acc[4][4] = {};

    for (int kt = 0; kt < DD / 64; ++kt) {
        const int k0 = kt * 64;
        // ---- stage A and B tiles ----
#pragma unroll
        for (int j = 0; j < 4; ++j) {
            const int c = wid * 4 + j;            // chunk 0..15, 1KB each (8 rows)
            const int arow = c * 8 + srow;        // row within 128-row tile
            const unsigned short* ga = Xb + (size_t)(m0 + arow) * DD + k0 + scol;
            const unsigned short* gb = Pb + (size_t)(n0 + arow) * DD + k0 + scol;
            __builtin_amdgcn_global_load_lds(
                (const __attribute__((address_space(1))) void*)ga,
                (__attribute__((address_space(3))) void*)((char*)As + c * 1024), 16, 0, 0);
            __builtin_amdgcn_global_load_lds(
                (const __attribute__((address_space(1))) void*)gb,
                (__attribute__((address_space(3))) void*)((char*)Bs + c * 1024), 16, 0, 0);
        }
        __syncthreads();   // drains vmcnt -> tiles ready

        const int sub = lane & 15, g = lane >> 4;
#pragma unroll
        for (int kk = 0; kk < 2; ++kk) {
            bf16x8 a[4], b[4];
#pragma unroll
            for (int m = 0; m < 4; ++m)
                a[m] = *(const bf16x8*)&As[(wr * 64 + m * 16 + sub) * 64 + kk * 32 + g * 8];
#pragma unroll
            for (int n = 0; n < 4; ++n)
                b[n] = *(const bf16x8*)&Bs[(wc * 64 + n * 16 + sub) * 64 + kk * 32 + g * 8];
#pragma unroll
            for (int m = 0; m < 4; ++m)
#pragma unroll
                for (int n = 0; n < 4; ++n)
                    acc[m][n] = __builtin_amdgcn_mfma_f32_16x16x32_bf16(a[m], b[n], acc[m][n], 0, 0, 0);
        }
        __syncthreads();   // all waves done reading before restage
    }

    // ---- fused epilogue: masked mins over this wave's 64 cols ----
    const int sub = lane & 15, g = lane >> 4;
    float psqv[4];
    int   lab[4];
#pragma unroll
    for (int n = 0; n < 4; ++n) {
        const int col = n0 + wc * 64 + n * 16 + sub;
        psqv[n] = psq[col];
        lab[n]  = col >> 2;   // prototype label = col / PPC
    }
    const int part = blockIdx.y * 2 + wc;
#pragma unroll
    for (int m = 0; m < 4; ++m) {
#pragma unroll
        for (int r = 0; r < 4; ++r) {
            const int row = m0 + wr * 64 + m * 16 + g * 4 + r;
            const float xs = xsq[row];
            const int yy = y[row];
            float d1 = BIGF, d2 = BIGF;
#pragma unroll
            for (int n = 0; n < 4; ++n) {
                const float dist = xs + psqv[n] - 2.0f * acc[m][n][r];
                if (lab[n] == yy) d1 = fminf(d1, dist);
                else              d2 = fminf(d2, dist);
            }
            for (int off = 8; off; off >>= 1) {
                d1 = fminf(d1, __shfl_xor(d1, off));
                d2 = fminf(d2, __shfl_xor(d2, off));
            }
            if (sub == 0) {
                d1p[part * NS + row] = d1;
                d2p[part * NS + row] = d2;
            }
        }
    }
}

__global__ __launch_bounds__(256) void finalize_kernel(
    const float* __restrict__ d1p, const float* __restrict__ d2p,
    const int* __restrict__ tval, float* __restrict__ out)
{
    const int row = blockIdx.x * 256 + threadIdx.x;
    float d1 = BIGF, d2 = BIGF;
#pragma unroll
    for (int p = 0; p < NPARTS; ++p) {
        d1 = fminf(d1, d1p[p * NS + row]);
        d2 = fminf(d2, d2p[p * NS + row]);
    }
    const float mu = (d1 - d2) / (d1 + d2 + EPSF);
    const float alpha = logf(1.0f + (float)tval[0]);
    float s = 1.0f / (1.0f + expf(-alpha * mu));
    for (int off = 32; off; off >>= 1) s += __shfl_down(s, off);
    __shared__ float red[4];
    if ((threadIdx.x & 63) == 0) red[threadIdx.x >> 6] = s;
    __syncthreads();
    if (threadIdx.x == 0)
        atomicAdd(out, (red[0] + red[1] + red[2] + red[3]) * (1.0f / (float)NS));
}

extern "C" void kernel_launch(void* const* d_in, const int* in_sizes, int n_in,
                              void* d_out, int out_size, void* d_ws, size_t ws_size,
                              hipStream_t stream) {
    const float* x      = (const float*)d_in[0];
    const int*   y      = (const int*)d_in[1];
    const int*   tval   = (const int*)d_in[2];
    const float* protos = (const float*)d_in[3];
    float* out = (float*)d_out;

    char* ws = (char*)d_ws;
    unsigned short* xb  = (unsigned short*)(ws);                               // 16 MB
    unsigned short* pb  = (unsigned short*)(ws + (size_t)NS * DD * 2);         // 1 MB
    float* xsq = (float*)(ws + (size_t)(NS + NP) * DD * 2);                    // 32 KB
    float* psq = (float*)(ws + (size_t)(NS + NP) * DD * 2 + NS * 4);           // 2 KB
    float* d1p = (float*)(ws + (size_t)(NS + NP) * DD * 2 + (NS + NP) * 4);    // 256 KB
    float* d2p = d1p + (size_t)NPARTS * NS;                                    // 256 KB

    prep_kernel<<<NS + NP, 256, 0, stream>>>(x, protos, xb, pb, xsq, psq);
    glvq_gemm<<<dim3(NS / 128, NP / 128), 256, 0, stream>>>(xb, pb, xsq, psq, y, d1p, d2p);
    (void)hipMemsetAsync(d_out, 0, sizeof(float), stream);
    finalize_kernel<<<NS / 256, 256, 0, stream>>>(d1p, d2p, tval, out);
}

// Round 3
// 37.856 us; speedup vs baseline: 1.2529x; 1.2529x over previous
//
#include <hip/hip_runtime.h>
#include <hip/hip_bf16.h>
#include <math.h>
#include <stdint.h>

#define NS 8192       // samples
#define DD 1024       // feature dim
#define NP 512        // prototypes
#define NPARTS 16     // 8 col-blocks * 2 wave-col-halves
#define EPSF 1e-9f
#define BIGF 3.0e38f

typedef __attribute__((ext_vector_type(8))) short bf16x8;
typedef __attribute__((ext_vector_type(4))) float f32x4;

__device__ inline unsigned short f32_to_bf16(float f) {
    uint32_t u = __builtin_bit_cast(uint32_t, f);
    uint32_t r = (u + 0x7FFFu + ((u >> 16) & 1u)) >> 16;
    return (unsigned short)r;
}

// One block per row (x rows then proto rows): convert to bf16, compute sum of squares (f32).
__global__ __launch_bounds__(256) void prep_kernel(
    const float* __restrict__ x, const float* __restrict__ protos,
    unsigned short* __restrict__ xb, unsigned short* __restrict__ pb,
    float* __restrict__ xsq, float* __restrict__ psq)
{
    int row = blockIdx.x;
    const float* src;
    unsigned short* dstb;
    float* dsts;
    if (row < NS) {
        src = x + (size_t)row * DD; dstb = xb + (size_t)row * DD; dsts = xsq + row;
    } else {
        int r = row - NS;
        src = protos + (size_t)r * DD; dstb = pb + (size_t)r * DD; dsts = psq + r;
    }
    int t = threadIdx.x;
    float4 v = ((const float4*)src)[t];
    float ss = v.x * v.x + v.y * v.y + v.z * v.z + v.w * v.w;
    ushort4 o;
    o.x = f32_to_bf16(v.x); o.y = f32_to_bf16(v.y);
    o.z = f32_to_bf16(v.z); o.w = f32_to_bf16(v.w);
    ((ushort4*)dstb)[t] = o;
    for (int off = 32; off; off >>= 1) ss += __shfl_down(ss, off);
    __shared__ float red[4];
    if ((t & 63) == 0) red[t >> 6] = ss;
    __syncthreads();
    if (t == 0) dsts[0] = red[0] + red[1] + red[2] + red[3];
}

// 64x64 bf16 MFMA tile, BK=64, 4 waves (2x2 of 32x32), global_load_lds staging
// with XOR-swizzled LDS layout: LDS[r][c16] = global[r][c16 ^ (r&7)].
// Grid: 1024 blocks, XCD-aware decode (each XCD: 16 M-blocks x 8 N-blocks -> 3MB L2-resident).
__global__ __launch_bounds__(256) void glvq_gemm(
    const unsigned short* __restrict__ Xb, const unsigned short* __restrict__ Pb,
    const float* __restrict__ xsq, const float* __restrict__ psq,
    const int* __restrict__ y,
    float* __restrict__ d1p, float* __restrict__ d2p)
{
    __shared__ unsigned short As[64 * 64];
    __shared__ unsigned short Bs[64 * 64];

    const int tid  = threadIdx.x;
    const int lane = tid & 63;
    const int wid  = tid >> 6;           // 0..3
    const int wr = wid >> 1, wc = wid & 1;

    // XCD-aware decode: dispatch d -> xcd d%8; xcd k owns M-blocks [k*16, k*16+16), all 8 N-blocks
    const int d    = blockIdx.x;         // 0..1023
    const int xcd  = d & 7;
    const int slot = d >> 3;             // 0..127
    const int mb   = xcd * 16 + (slot & 15);
    const int nb   = slot >> 4;          // 0..7
    const int m0   = mb * 64;
    const int n0   = nb * 64;

    // staging: lane l loads 16B for row (l>>3), swizzled source chunk
    const int srow   = lane >> 3;                    // 0..7
    const int scol16 = (lane & 7) ^ srow;            // pre-swizzled global 16B-chunk
    const int sub = lane & 15, g = lane >> 4;

    f32x4 acc[2][2] = {};

    for (int kt = 0; kt < DD / 64; ++kt) {
        const int k0 = kt * 64;
#pragma unroll
        for (int j = 0; j < 2; ++j) {
            const int row = j * 32 + wid * 8;        // wave-uniform base row (8 rows/wave)
            const unsigned short* ga = Xb + (size_t)(m0 + row + srow) * DD + k0 + scol16 * 8;
            const unsigned short* gb = Pb + (size_t)(n0 + row + srow) * DD + k0 + scol16 * 8;
            __builtin_amdgcn_global_load_lds(
                (const __attribute__((address_space(1))) void*)ga,
                (__attribute__((address_space(3))) void*)((char*)As + row * 128), 16, 0, 0);
            __builtin_amdgcn_global_load_lds(
                (const __attribute__((address_space(1))) void*)gb,
                (__attribute__((address_space(3))) void*)((char*)Bs + row * 128), 16, 0, 0);
        }
        __syncthreads();   // drains vmcnt -> tiles ready

#pragma unroll
        for (int kk = 0; kk < 2; ++kk) {
            bf16x8 a[2], b[2];
#pragma unroll
            for (int m = 0; m < 2; ++m) {
                const int row = wr * 32 + m * 16 + sub;
                const int c16 = (kk * 4 + g) ^ (row & 7);
                a[m] = *(const bf16x8*)((const char*)As + row * 128 + c16 * 16);
            }
#pragma unroll
            for (int n = 0; n < 2; ++n) {
                const int row = wc * 32 + n * 16 + sub;
                const int c16 = (kk * 4 + g) ^ (row & 7);
                b[n] = *(const bf16x8*)((const char*)Bs + row * 128 + c16 * 16);
            }
#pragma unroll
            for (int m = 0; m < 2; ++m)
#pragma unroll
                for (int n = 0; n < 2; ++n)
                    acc[m][n] = __builtin_amdgcn_mfma_f32_16x16x32_bf16(a[m], b[n], acc[m][n], 0, 0, 0);
        }
        __syncthreads();   // all waves done reading before restage
    }

    // ---- fused epilogue: masked mins over this wave's 32 cols ----
    float psqv[2];
    int   lab[2];
#pragma unroll
    for (int n = 0; n < 2; ++n) {
        const int col = n0 + wc * 32 + n * 16 + sub;
        psqv[n] = psq[col];
        lab[n]  = col >> 2;   // prototype label = col / PPC
    }
    const int part = nb * 2 + wc;
#pragma unroll
    for (int m = 0; m < 2; ++m) {
#pragma unroll
        for (int r = 0; r < 4; ++r) {
            const int row = m0 + wr * 32 + m * 16 + g * 4 + r;
            const float xs = xsq[row];
            const int yy = y[row];
            float d1 = BIGF, d2 = BIGF;
#pragma unroll
            for (int n = 0; n < 2; ++n) {
                const float dist = xs + psqv[n] - 2.0f * acc[m][n][r];
                if (lab[n] == yy) d1 = fminf(d1, dist);
                else              d2 = fminf(d2, dist);
            }
            for (int off = 8; off; off >>= 1) {
                d1 = fminf(d1, __shfl_xor(d1, off));
                d2 = fminf(d2, __shfl_xor(d2, off));
            }
            if (sub == 0) {
                d1p[part * NS + row] = d1;
                d2p[part * NS + row] = d2;
            }
        }
    }
}

__global__ __launch_bounds__(256) void finalize_kernel(
    const float* __restrict__ d1p, const float* __restrict__ d2p,
    const int* __restrict__ tval, float* __restrict__ bsum)
{
    const int row = blockIdx.x * 256 + threadIdx.x;
    float d1 = BIGF, d2 = BIGF;
#pragma unroll
    for (int p = 0; p < NPARTS; ++p) {
        d1 = fminf(d1, d1p[p * NS + row]);
        d2 = fminf(d2, d2p[p * NS + row]);
    }
    const float mu = (d1 - d2) / (d1 + d2 + EPSF);
    const float alpha = logf(1.0f + (float)tval[0]);
    float s = 1.0f / (1.0f + expf(-alpha * mu));
    for (int off = 32; off; off >>= 1) s += __shfl_down(s, off);
    __shared__ float red[4];
    if ((threadIdx.x & 63) == 0) red[threadIdx.x >> 6] = s;
    __syncthreads();
    if (threadIdx.x == 0) bsum[blockIdx.x] = red[0] + red[1] + red[2] + red[3];
}

__global__ void final_sum(const float* __restrict__ bsum, float* __restrict__ out) {
    float s = (threadIdx.x < NS / 256) ? bsum[threadIdx.x] : 0.0f;
    for (int off = 32; off; off >>= 1) s += __shfl_down(s, off);
    if (threadIdx.x == 0) out[0] = s * (1.0f / (float)NS);
}

extern "C" void kernel_launch(void* const* d_in, const int* in_sizes, int n_in,
                              void* d_out, int out_size, void* d_ws, size_t ws_size,
                              hipStream_t stream) {
    const float* x      = (const float*)d_in[0];
    const int*   y      = (const int*)d_in[1];
    const int*   tval   = (const int*)d_in[2];
    const float* protos = (const float*)d_in[3];
    float* out = (float*)d_out;

    char* ws = (char*)d_ws;
    unsigned short* xb  = (unsigned short*)(ws);                               // 16 MB
    unsigned short* pb  = (unsigned short*)(ws + (size_t)NS * DD * 2);         // 1 MB
    float* xsq  = (float*)(ws + (size_t)(NS + NP) * DD * 2);                   // 32 KB
    float* psq  = (float*)(ws + (size_t)(NS + NP) * DD * 2 + NS * 4);          // 2 KB
    float* d1p  = (float*)(ws + (size_t)(NS + NP) * DD * 2 + (NS + NP) * 4);   // 512 KB
    float* d2p  = d1p + (size_t)NPARTS * NS;                                   // 512 KB
    float* bsum = d2p + (size_t)NPARTS * NS;                                   // 128 B

    prep_kernel<<<NS + NP, 256, 0, stream>>>(x, protos, xb, pb, xsq, psq);
    glvq_gemm<<<(NS / 64) * (NP / 64), 256, 0, stream>>>(xb, pb, xsq, psq, y, d1p, d2p);
    finalize_kernel<<<NS / 256, 256, 0, stream>>>(d1p, d2p, tval, bsum);
    final_sum<<<1, 64, 0, stream>>>(bsum, out);
}

// Round 4
// 37.412 us; speedup vs baseline: 1.2677x; 1.0119x over previous
//
#include <hip/hip_runtime.h>
#include <hip/hip_bf16.h>
#include <math.h>
#include <stdint.h>

#define NS 8192       // samples
#define DD 1024       // feature dim
#define NP 512        // prototypes
#define NPARTS 8      // 4 N-blocks * 2 wave-col-halves
#define EPSF 1e-9f
#define BIGF 3.0e38f

typedef __attribute__((ext_vector_type(8))) short bf16x8;
typedef __attribute__((ext_vector_type(4))) float f32x4;

__device__ inline unsigned short f32_to_bf16(float f) {
    uint32_t u = __builtin_bit_cast(uint32_t, f);
    uint32_t r = (u + 0x7FFFu + ((u >> 16) & 1u)) >> 16;
    return (unsigned short)r;
}

// One block per row (x rows then proto rows): convert to bf16, compute sum of squares (f32).
__global__ __launch_bounds__(256) void prep_kernel(
    const float* __restrict__ x, const float* __restrict__ protos,
    unsigned short* __restrict__ xb, unsigned short* __restrict__ pb,
    float* __restrict__ xsq, float* __restrict__ psq)
{
    int row = blockIdx.x;
    const float* src;
    unsigned short* dstb;
    float* dsts;
    if (row < NS) {
        src = x + (size_t)row * DD; dstb = xb + (size_t)row * DD; dsts = xsq + row;
    } else {
        int r = row - NS;
        src = protos + (size_t)r * DD; dstb = pb + (size_t)r * DD; dsts = psq + r;
    }
    int t = threadIdx.x;
    float4 v = ((const float4*)src)[t];
    float ss = v.x * v.x + v.y * v.y + v.z * v.z + v.w * v.w;
    ushort4 o;
    o.x = f32_to_bf16(v.x); o.y = f32_to_bf16(v.y);
    o.z = f32_to_bf16(v.z); o.w = f32_to_bf16(v.w);
    ((ushort4*)dstb)[t] = o;
    for (int off = 32; off; off >>= 1) ss += __shfl_down(ss, off);
    __shared__ float red[4];
    if ((t & 63) == 0) red[t >> 6] = ss;
    __syncthreads();
    if (t == 0) dsts[0] = red[0] + red[1] + red[2] + red[3];
}

// 64x128 bf16 MFMA tile, BK=64, 4 waves (2x2 of 32x64), 2-phase double-buffered
// global_load_lds staging, XOR-swizzled LDS: LDS[r][c16] = global[r][c16 ^ (r&7)].
// Grid: 512 blocks (2/CU), XCD-bijective decode (per XCD: 16 M-blocks x 4 N-blocks).
__global__ __launch_bounds__(256) void glvq_gemm(
    const unsigned short* __restrict__ Xb, const unsigned short* __restrict__ Pb,
    const float* __restrict__ xsq, const float* __restrict__ psq,
    const int* __restrict__ y,
    float* __restrict__ d1p, float* __restrict__ d2p)
{
    __shared__ unsigned short As[2][64 * 64];    // 2 x 8 KB
    __shared__ unsigned short Bs[2][128 * 64];   // 2 x 16 KB

    const int tid  = threadIdx.x;
    const int lane = tid & 63;
    const int wid  = tid >> 6;           // 0..3
    const int wr = wid >> 1, wc = wid & 1;

    const int d    = blockIdx.x;         // 0..511
    const int xcd  = d & 7;
    const int slot = d >> 3;             // 0..63
    const int mb   = xcd * 16 + (slot & 15);  // 0..127
    const int nb   = slot >> 4;               // 0..3
    const int m0   = mb * 64;
    const int n0   = nb * 128;

    // staging: lane l covers row (l>>3) of an 8-row chunk, pre-swizzled source col-chunk
    const int srow   = lane >> 3;
    const int scol16 = (lane & 7) ^ srow;
    const int sub = lane & 15, g = lane >> 4;

    f32x4 acc[2][4] = {};

    auto stage = [&](int buf, int kt) {
        const int k0 = kt * 64;
        // A: 8 chunks of 8 rows; wave w stages chunks {2w, 2w+1}
#pragma unroll
        for (int j = 0; j < 2; ++j) {
            const int c = wid * 2 + j;
            const unsigned short* ga = Xb + (size_t)(m0 + c * 8 + srow) * DD + k0 + scol16 * 8;
            __builtin_amdgcn_global_load_lds(
                (const __attribute__((address_space(1))) void*)ga,
                (__attribute__((address_space(3))) void*)((char*)&As[buf][0] + c * 1024), 16, 0, 0);
        }
        // B: 16 chunks; wave w stages chunks {4w..4w+3}
#pragma unroll
        for (int j = 0; j < 4; ++j) {
            const int c = wid * 4 + j;
            const unsigned short* gb = Pb + (size_t)(n0 + c * 8 + srow) * DD + k0 + scol16 * 8;
            __builtin_amdgcn_global_load_lds(
                (const __attribute__((address_space(1))) void*)gb,
                (__attribute__((address_space(3))) void*)((char*)&Bs[buf][0] + c * 1024), 16, 0, 0);
        }
    };

    auto compute = [&](int buf) {
#pragma unroll
        for (int kk = 0; kk < 2; ++kk) {
            bf16x8 a[2], b[4];
#pragma unroll
            for (int m = 0; m < 2; ++m) {
                const int row = wr * 32 + m * 16 + sub;
                const int c16 = (kk * 4 + g) ^ (row & 7);
                a[m] = *(const bf16x8*)((const char*)&As[buf][0] + row * 128 + c16 * 16);
            }
#pragma unroll
            for (int n = 0; n < 4; ++n) {
                const int row = wc * 64 + n * 16 + sub;
                const int c16 = (kk * 4 + g) ^ (row & 7);
                b[n] = *(const bf16x8*)((const char*)&Bs[buf][0] + row * 128 + c16 * 16);
            }
#pragma unroll
            for (int m = 0; m < 2; ++m)
#pragma unroll
                for (int n = 0; n < 4; ++n)
                    acc[m][n] = __builtin_amdgcn_mfma_f32_16x16x32_bf16(a[m], b[n], acc[m][n], 0, 0, 0);
        }
    };

    // 2-phase pipeline: loads for tile kt+1 fly while tile kt computes.
    stage(0, 0);
    __syncthreads();
    int cur = 0;
#pragma unroll 1
    for (int kt = 0; kt < DD / 64 - 1; ++kt) {
        stage(cur ^ 1, kt + 1);
        compute(cur);
        __syncthreads();       // drains next-tile vmcnt; cur buffer free for restage
        cur ^= 1;
    }
    compute(cur);              // epilogue tile, no barrier (LDS not reused)

    // ---- fused epilogue: masked mins over this wave's 64 cols ----
    float psqv[4];
    int   lab[4];
#pragma unroll
    for (int n = 0; n < 4; ++n) {
        const int col = n0 + wc * 64 + n * 16 + sub;
        psqv[n] = psq[col];
        lab[n]  = col >> 2;   // prototype label = col / PPC
    }
    const int part = nb * 2 + wc;
#pragma unroll
    for (int m = 0; m < 2; ++m) {
#pragma unroll
        for (int r = 0; r < 4; ++r) {
            const int row = m0 + wr * 32 + m * 16 + g * 4 + r;
            const float xs = xsq[row];
            const int yy = y[row];
            float d1 = BIGF, d2 = BIGF;
#pragma unroll
            for (int n = 0; n < 4; ++n) {
                const float dist = xs + psqv[n] - 2.0f * acc[m][n][r];
                if (lab[n] == yy) d1 = fminf(d1, dist);
                else              d2 = fminf(d2, dist);
            }
            for (int off = 8; off; off >>= 1) {
                d1 = fminf(d1, __shfl_xor(d1, off));
                d2 = fminf(d2, __shfl_xor(d2, off));
            }
            if (sub == 0) {
                d1p[part * NS + row] = d1;
                d2p[part * NS + row] = d2;
            }
        }
    }
}

__global__ __launch_bounds__(256) void finalize_kernel(
    const float* __restrict__ d1p, const float* __restrict__ d2p,
    const int* __restrict__ tval, float* __restrict__ bsum)
{
    const int row = blockIdx.x * 256 + threadIdx.x;
    float d1 = BIGF, d2 = BIGF;
#pragma unroll
    for (int p = 0; p < NPARTS; ++p) {
        d1 = fminf(d1, d1p[p * NS + row]);
        d2 = fminf(d2, d2p[p * NS + row]);
    }
    const float mu = (d1 - d2) / (d1 + d2 + EPSF);
    const float alpha = logf(1.0f + (float)tval[0]);
    float s = 1.0f / (1.0f + expf(-alpha * mu));
    for (int off = 32; off; off >>= 1) s += __shfl_down(s, off);
    __shared__ float red[4];
    if ((threadIdx.x & 63) == 0) red[threadIdx.x >> 6] = s;
    __syncthreads();
    if (threadIdx.x == 0) bsum[blockIdx.x] = red[0] + red[1] + red[2] + red[3];
}

__global__ void final_sum(const float* __restrict__ bsum, float* __restrict__ out) {
    float s = (threadIdx.x < NS / 256) ? bsum[threadIdx.x] : 0.0f;
    for (int off = 32; off; off >>= 1) s += __shfl_down(s, off);
    if (threadIdx.x == 0) out[0] = s * (1.0f / (float)NS);
}

extern "C" void kernel_launch(void* const* d_in, const int* in_sizes, int n_in,
                              void* d_out, int out_size, void* d_ws, size_t ws_size,
                              hipStream_t stream) {
    const float* x      = (const float*)d_in[0];
    const int*   y      = (const int*)d_in[1];
    const int*   tval   = (const int*)d_in[2];
    const float* protos = (const float*)d_in[3];
    float* out = (float*)d_out;

    char* ws = (char*)d_ws;
    unsigned short* xb  = (unsigned short*)(ws);                               // 16 MB
    unsigned short* pb  = (unsigned short*)(ws + (size_t)NS * DD * 2);         // 1 MB
    float* xsq  = (float*)(ws + (size_t)(NS + NP) * DD * 2);                   // 32 KB
    float* psq  = (float*)(ws + (size_t)(NS + NP) * DD * 2 + NS * 4);          // 2 KB
    float* d1p  = (float*)(ws + (size_t)(NS + NP) * DD * 2 + (NS + NP) * 4);   // 256 KB
    float* d2p  = d1p + (size_t)NPARTS * NS;                                   // 256 KB
    float* bsum = d2p + (size_t)NPARTS * NS;                                   // 128 B

    prep_kernel<<<NS + NP, 256, 0, stream>>>(x, protos, xb, pb, xsq, psq);
    glvq_gemm<<<(NS / 64) * (NP / 128), 256, 0, stream>>>(xb, pb, xsq, psq, y, d1p, d2p);
    finalize_kernel<<<NS / 256, 256, 0, stream>>>(d1p, d2p, tval, bsum);
    final_sum<<<1, 64, 0, stream>>>(bsum, out);
}